// Round 9
// baseline (462.613 us; speedup 1.0000x reference)
//
#include <hip/hip_runtime.h>

#define N_NODES_C 100000
#define N_EDGES_C 1600000
#define IN_F 64
#define OUT_F 64
#define NK 4
#define SCAN_BLK 256
#define NBLK ((N_NODES_C + SCAN_BLK - 1) / SCAN_BLK)   // 391
#define EBLK (N_EDGES_C / 256)                         // 6250 exact

__device__ __forceinline__ unsigned int f2bf(float x) {
    unsigned int u = __float_as_uint(x);
    return (u + 0x7fffu + ((u >> 16) & 1u)) >> 16;
}
__device__ __forceinline__ float bflo(unsigned int u) { return __uint_as_float(u << 16); }
__device__ __forceinline__ float bfhi(unsigned int u) { return __uint_as_float(u & 0xffff0000u); }

// ---------------------------------------------------------------------------
// hist + gaussian weights, edge-parallel, fully coalesced
// ---------------------------------------------------------------------------
__global__ __launch_bounds__(256) void hist_gauss_kernel(
    const int* __restrict__ dst, const float* __restrict__ pseudo,
    const float* __restrict__ mu, const float* __restrict__ inv_sigma,
    int* __restrict__ cnt, uint2* __restrict__ g8)
{
    const int e = blockIdx.x * 256 + threadIdx.x;
    if (e >= N_EDGES_C) return;
    atomicAdd(&cnt[dst[e]], 1);
    const float p0 = pseudo[(size_t)e * 3 + 0];
    const float p1 = pseudo[(size_t)e * 3 + 1];
    const float p2 = pseudo[(size_t)e * 3 + 2];
    float g[NK];
    #pragma unroll
    for (int k = 0; k < NK; ++k) {
        const float d0 = p0 - mu[k*3+0], d1 = p1 - mu[k*3+1], d2 = p2 - mu[k*3+2];
        const float s0 = inv_sigma[k*3+0], s1 = inv_sigma[k*3+1], s2 = inv_sigma[k*3+2];
        const float ex = -0.5f * (d0*d0*s0*s0 + d1*d1*s1*s1 + d2*d2*s2*s2);
        g[k] = __expf(ex);
    }
    uint2 r;
    r.x = f2bf(g[0]) | (f2bf(g[1]) << 16);
    r.y = f2bf(g[2]) | (f2bf(g[3]) << 16);
    g8[e] = r;
}

// ---------------------------------------------------------------------------
// proj (R2 structure — no spill): thread t owns output col t=(o,k);
// scalar wreg[64]; feat row via LDS; coalesced 2B stores.
// ---------------------------------------------------------------------------
__global__ __launch_bounds__(256, 2) void proj_kernel(
    const float* __restrict__ feat, const float* __restrict__ W,
    unsigned short* __restrict__ hb, int n_nodes)
{
    __shared__ float frow[IN_F];
    const int t = threadIdx.x;
    const int o = t >> 2;
    const int k = t & 3;
    float wreg[IN_F];
    {
        const float4* W4 = reinterpret_cast<const float4*>(W + (size_t)(k * OUT_F + o) * IN_F);
        #pragma unroll
        for (int i = 0; i < IN_F / 4; ++i) {
            float4 v = W4[i];
            wreg[4*i+0] = v.x; wreg[4*i+1] = v.y; wreg[4*i+2] = v.z; wreg[4*i+3] = v.w;
        }
    }
    for (int n = blockIdx.x; n < n_nodes; n += gridDim.x) {
        if (t < IN_F / 4) {
            float4 v = reinterpret_cast<const float4*>(feat + (size_t)n * IN_F)[t];
            frow[4*t+0] = v.x; frow[4*t+1] = v.y; frow[4*t+2] = v.z; frow[4*t+3] = v.w;
        }
        __syncthreads();
        float acc = 0.f;
        #pragma unroll
        for (int i = 0; i < IN_F; ++i) acc = fmaf(frow[i], wreg[i], acc);
        hb[(size_t)n * 256 + t] = (unsigned short)f2bf(acc);
        __syncthreads();
    }
}

// ---------------------------------------------------------------------------
// scan1: per-block sums of cnt
// ---------------------------------------------------------------------------
__global__ __launch_bounds__(256) void scan1_kernel(
    const int* __restrict__ cnt, int* __restrict__ bsum)
{
    __shared__ int s[SCAN_BLK];
    int i = blockIdx.x * SCAN_BLK + threadIdx.x;
    int v = (i < N_NODES_C) ? cnt[i] : 0;
    s[threadIdx.x] = v; __syncthreads();
    for (int off = SCAN_BLK / 2; off > 0; off >>= 1) {
        if (threadIdx.x < off) s[threadIdx.x] += s[threadIdx.x + off];
        __syncthreads();
    }
    if (threadIdx.x == 0) bsum[blockIdx.x] = s[0];
}

// ---------------------------------------------------------------------------
// scan23: block-prefix over bsum + local exclusive scan -> row_start, cursor
// ---------------------------------------------------------------------------
__global__ __launch_bounds__(256) void scan23_kernel(
    const int* __restrict__ cnt, const int* __restrict__ bsum,
    int* __restrict__ row_start, int* __restrict__ cursor)
{
    __shared__ int pre[SCAN_BLK];
    __shared__ int s[SCAN_BLK];
    const int t = threadIdx.x;
    int p = 0;
    for (int i = t; i < (int)blockIdx.x; i += SCAN_BLK) p += bsum[i];
    pre[t] = p; __syncthreads();
    for (int off = SCAN_BLK / 2; off > 0; off >>= 1) {
        if (t < off) pre[t] += pre[t + off];
        __syncthreads();
    }
    const int boff = pre[0];
    const int i = blockIdx.x * SCAN_BLK + t;
    int v = (i < N_NODES_C) ? cnt[i] : 0;
    s[t] = v; __syncthreads();
    for (int off = 1; off < SCAN_BLK; off <<= 1) {
        int x = (t >= off) ? s[t - off] : 0;
        __syncthreads();
        s[t] += x;
        __syncthreads();
    }
    if (i < N_NODES_C) {
        int ex = s[t] - v + boff;
        row_start[i] = ex;
        cursor[i] = ex;
        if (i == N_NODES_C - 1) row_start[N_NODES_C] = ex + v;
    }
}

// ---------------------------------------------------------------------------
// scatter: only invert the permutation — 4B random store into 6.4MB
// (L2-resident region -> write-coalescing in cache)
// ---------------------------------------------------------------------------
__global__ __launch_bounds__(256) void scatter_kernel(
    const int* __restrict__ dst, int* __restrict__ cursor,
    int* __restrict__ perm)
{
    const int e = blockIdx.x * 256 + threadIdx.x;
    if (e >= N_EDGES_C) return;
    const int d = dst[e];
    const int pos = atomicAdd(&cursor[d], 1);
    perm[pos] = e;
}

// ---------------------------------------------------------------------------
// reorder: materialize sorted records. Coalesced perm read, random (L2-hot)
// src/g8 gathers, fully coalesced 16B rec writes.
// ---------------------------------------------------------------------------
__global__ __launch_bounds__(256) void reorder_kernel(
    const int* __restrict__ perm, const int* __restrict__ src,
    const uint2* __restrict__ g8, uint4* __restrict__ rec)
{
    const int pos = blockIdx.x * 256 + threadIdx.x;
    if (pos >= N_EDGES_C) return;
    const int e = perm[pos];
    const int s = src[e];
    const uint2 g = g8[e];
    uint4 r; r.x = (unsigned int)s; r.y = g.x; r.z = g.y; r.w = 0u;
    rec[pos] = r;
}

// ---------------------------------------------------------------------------
// gather: one wave per dst node, lane = output feature, unroll x4 for MLP.
// ---------------------------------------------------------------------------
__global__ __launch_bounds__(256) void gather_kernel(
    const int* __restrict__ row_start, const uint4* __restrict__ rec,
    const unsigned short* __restrict__ hb,
    const float* __restrict__ feat, const float* __restrict__ bias,
    float* __restrict__ out, int n_nodes)
{
    const int lane = threadIdx.x & 63;
    const int v = (blockIdx.x * 256 + threadIdx.x) >> 6;
    if (v >= n_nodes) return;
    const int r0 = row_start[v];
    const int r1 = row_start[v + 1];
    float acc = 0.f;
    int j = r0;
    for (; j + 4 <= r1; j += 4) {
        const uint4 ra = rec[j+0];
        const uint4 rb = rec[j+1];
        const uint4 rc = rec[j+2];
        const uint4 rd = rec[j+3];
        const uint2 ha = *(const uint2*)(hb + (size_t)ra.x * 256 + lane * 4);
        const uint2 hbv= *(const uint2*)(hb + (size_t)rb.x * 256 + lane * 4);
        const uint2 hc = *(const uint2*)(hb + (size_t)rc.x * 256 + lane * 4);
        const uint2 hd = *(const uint2*)(hb + (size_t)rd.x * 256 + lane * 4);
        acc += bflo(ra.y)*bflo(ha.x) + bfhi(ra.y)*bfhi(ha.x)
             + bflo(ra.z)*bflo(ha.y) + bfhi(ra.z)*bfhi(ha.y);
        acc += bflo(rb.y)*bflo(hbv.x) + bfhi(rb.y)*bfhi(hbv.x)
             + bflo(rb.z)*bflo(hbv.y) + bfhi(rb.z)*bfhi(hbv.y);
        acc += bflo(rc.y)*bflo(hc.x) + bfhi(rc.y)*bfhi(hc.x)
             + bflo(rc.z)*bflo(hc.y) + bfhi(rc.z)*bfhi(hc.y);
        acc += bflo(rd.y)*bflo(hd.x) + bfhi(rd.y)*bfhi(hd.x)
             + bflo(rd.z)*bflo(hd.y) + bfhi(rd.z)*bfhi(hd.y);
    }
    for (; j < r1; ++j) {
        const uint4 ra = rec[j];
        const uint2 ha = *(const uint2*)(hb + (size_t)ra.x * 256 + lane * 4);
        acc += bflo(ra.y)*bflo(ha.x) + bfhi(ra.y)*bfhi(ha.x)
             + bflo(ra.z)*bflo(ha.y) + bfhi(ra.z)*bfhi(ha.y);
    }
    out[(size_t)v * OUT_F + lane] = acc + feat[(size_t)v * OUT_F + lane] + bias[lane];
}

extern "C" void kernel_launch(void* const* d_in, const int* in_sizes, int n_in,
                              void* d_out, int out_size, void* d_ws, size_t ws_size,
                              hipStream_t stream) {
    const float* feat      = (const float*)d_in[0];
    const float* pseudo    = (const float*)d_in[1];
    const int*   src       = (const int*)d_in[2];
    const int*   dst       = (const int*)d_in[3];
    const float* W_fc      = (const float*)d_in[4];
    const float* mu        = (const float*)d_in[5];
    const float* inv_sigma = (const float*)d_in[6];
    const float* bias      = (const float*)d_in[7];
    float* out = (float*)d_out;

    char* ws = (char*)d_ws;
    unsigned short* hb = (unsigned short*)ws;  ws += (size_t)N_NODES_C * 256 * 2;   // 51.2 MB
    uint2* g8          = (uint2*)ws;           ws += (size_t)N_EDGES_C * 8;         // 12.8 MB
    uint4* rec         = (uint4*)ws;           ws += (size_t)N_EDGES_C * 16;        // 25.6 MB
    int* perm          = (int*)ws;             ws += (size_t)N_EDGES_C * 4;         // 6.4 MB
    int* cnt           = (int*)ws;             ws += (size_t)N_NODES_C * 4;
    int* row_start     = (int*)ws;             ws += (size_t)(N_NODES_C + 4) * 4;
    int* cursor        = (int*)ws;             ws += (size_t)N_NODES_C * 4;
    int* bsum          = (int*)ws;             ws += 512 * 4;

    hipMemsetAsync(cnt, 0, (size_t)N_NODES_C * 4, stream);
    hist_gauss_kernel<<<EBLK, 256, 0, stream>>>(dst, pseudo, mu, inv_sigma, cnt, g8);
    proj_kernel<<<2048, 256, 0, stream>>>(feat, W_fc, hb, N_NODES_C);
    scan1_kernel<<<NBLK, SCAN_BLK, 0, stream>>>(cnt, bsum);
    scan23_kernel<<<NBLK, SCAN_BLK, 0, stream>>>(cnt, bsum, row_start, cursor);
    scatter_kernel<<<EBLK, 256, 0, stream>>>(dst, cursor, perm);
    reorder_kernel<<<EBLK, 256, 0, stream>>>(perm, src, g8, rec);
    gather_kernel<<<(N_NODES_C * 64 + 255) / 256, 256, 0, stream>>>(
        row_start, rec, hb, feat, bias, out, N_NODES_C);
}

// Round 10
// 397.202 us; speedup vs baseline: 1.1647x; 1.1647x over previous
//
#include <hip/hip_runtime.h>

#define N_NODES_C 100000
#define N_EDGES_C 1600000
#define IN_F 64
#define OUT_F 64
#define NK 4
#define SCAN_BLK 256
#define NBLK ((N_NODES_C + SCAN_BLK - 1) / SCAN_BLK)   // 391
#define EBLK (N_EDGES_C / 256)                         // 6250 exact
#define CPAD 16                                        // cursor stride: 1 per 64B line

__device__ __forceinline__ unsigned int f2bf(float x) {
    unsigned int u = __float_as_uint(x);
    return (u + 0x7fffu + ((u >> 16) & 1u)) >> 16;
}
__device__ __forceinline__ float bflo(unsigned int u) { return __uint_as_float(u << 16); }
__device__ __forceinline__ float bfhi(unsigned int u) { return __uint_as_float(u & 0xffff0000u); }

// ---------------------------------------------------------------------------
// hist + gaussian weights, edge-parallel, fully coalesced
// ---------------------------------------------------------------------------
__global__ __launch_bounds__(256) void hist_gauss_kernel(
    const int* __restrict__ dst, const float* __restrict__ pseudo,
    const float* __restrict__ mu, const float* __restrict__ inv_sigma,
    int* __restrict__ cnt, uint2* __restrict__ g8)
{
    const int e = blockIdx.x * 256 + threadIdx.x;
    if (e >= N_EDGES_C) return;
    atomicAdd(&cnt[dst[e]], 1);
    const float p0 = pseudo[(size_t)e * 3 + 0];
    const float p1 = pseudo[(size_t)e * 3 + 1];
    const float p2 = pseudo[(size_t)e * 3 + 2];
    float g[NK];
    #pragma unroll
    for (int k = 0; k < NK; ++k) {
        const float d0 = p0 - mu[k*3+0], d1 = p1 - mu[k*3+1], d2 = p2 - mu[k*3+2];
        const float s0 = inv_sigma[k*3+0], s1 = inv_sigma[k*3+1], s2 = inv_sigma[k*3+2];
        const float ex = -0.5f * (d0*d0*s0*s0 + d1*d1*s1*s1 + d2*d2*s2*s2);
        g[k] = __expf(ex);
    }
    uint2 r;
    r.x = f2bf(g[0]) | (f2bf(g[1]) << 16);
    r.y = f2bf(g[2]) | (f2bf(g[3]) << 16);
    g8[e] = r;
}

// ---------------------------------------------------------------------------
// proj (R2 structure — no spill): thread t owns output col t=(o,k);
// scalar wreg[64]; feat row via LDS; coalesced 2B stores.
// ---------------------------------------------------------------------------
__global__ __launch_bounds__(256, 2) void proj_kernel(
    const float* __restrict__ feat, const float* __restrict__ W,
    unsigned short* __restrict__ hb, int n_nodes)
{
    __shared__ float frow[IN_F];
    const int t = threadIdx.x;
    const int o = t >> 2;
    const int k = t & 3;
    float wreg[IN_F];
    {
        const float4* W4 = reinterpret_cast<const float4*>(W + (size_t)(k * OUT_F + o) * IN_F);
        #pragma unroll
        for (int i = 0; i < IN_F / 4; ++i) {
            float4 v = W4[i];
            wreg[4*i+0] = v.x; wreg[4*i+1] = v.y; wreg[4*i+2] = v.z; wreg[4*i+3] = v.w;
        }
    }
    for (int n = blockIdx.x; n < n_nodes; n += gridDim.x) {
        if (t < IN_F / 4) {
            float4 v = reinterpret_cast<const float4*>(feat + (size_t)n * IN_F)[t];
            frow[4*t+0] = v.x; frow[4*t+1] = v.y; frow[4*t+2] = v.z; frow[4*t+3] = v.w;
        }
        __syncthreads();
        float acc = 0.f;
        #pragma unroll
        for (int i = 0; i < IN_F; ++i) acc = fmaf(frow[i], wreg[i], acc);
        hb[(size_t)n * 256 + t] = (unsigned short)f2bf(acc);
        __syncthreads();
    }
}

// ---------------------------------------------------------------------------
// scan1: per-block sums of cnt
// ---------------------------------------------------------------------------
__global__ __launch_bounds__(256) void scan1_kernel(
    const int* __restrict__ cnt, int* __restrict__ bsum)
{
    __shared__ int s[SCAN_BLK];
    int i = blockIdx.x * SCAN_BLK + threadIdx.x;
    int v = (i < N_NODES_C) ? cnt[i] : 0;
    s[threadIdx.x] = v; __syncthreads();
    for (int off = SCAN_BLK / 2; off > 0; off >>= 1) {
        if (threadIdx.x < off) s[threadIdx.x] += s[threadIdx.x + off];
        __syncthreads();
    }
    if (threadIdx.x == 0) bsum[blockIdx.x] = s[0];
}

// ---------------------------------------------------------------------------
// scan23: block-prefix over bsum + local exclusive scan -> row_start,
// padded cursor (one counter per 64B line)
// ---------------------------------------------------------------------------
__global__ __launch_bounds__(256) void scan23_kernel(
    const int* __restrict__ cnt, const int* __restrict__ bsum,
    int* __restrict__ row_start, int* __restrict__ cursor_pad)
{
    __shared__ int pre[SCAN_BLK];
    __shared__ int s[SCAN_BLK];
    const int t = threadIdx.x;
    int p = 0;
    for (int i = t; i < (int)blockIdx.x; i += SCAN_BLK) p += bsum[i];
    pre[t] = p; __syncthreads();
    for (int off = SCAN_BLK / 2; off > 0; off >>= 1) {
        if (t < off) pre[t] += pre[t + off];
        __syncthreads();
    }
    const int boff = pre[0];
    const int i = blockIdx.x * SCAN_BLK + t;
    int v = (i < N_NODES_C) ? cnt[i] : 0;
    s[t] = v; __syncthreads();
    for (int off = 1; off < SCAN_BLK; off <<= 1) {
        int x = (t >= off) ? s[t - off] : 0;
        __syncthreads();
        s[t] += x;
        __syncthreads();
    }
    if (i < N_NODES_C) {
        int ex = s[t] - v + boff;
        row_start[i] = ex;
        cursor_pad[(size_t)i * CPAD] = ex;
        if (i == N_NODES_C - 1) row_start[N_NODES_C] = ex + v;
    }
}

// ---------------------------------------------------------------------------
// scatter: padded-cursor atomic (line-private per node) + 16B record store
// ---------------------------------------------------------------------------
__global__ __launch_bounds__(256) void scatter_kernel(
    const int* __restrict__ src, const int* __restrict__ dst,
    const uint2* __restrict__ g8, int* __restrict__ cursor_pad,
    uint4* __restrict__ rec)
{
    const int e = blockIdx.x * 256 + threadIdx.x;
    if (e >= N_EDGES_C) return;
    const int d = dst[e];
    const int s = src[e];
    const uint2 g = g8[e];
    const int pos = atomicAdd(&cursor_pad[(size_t)d * CPAD], 1);
    uint4 r; r.x = (unsigned int)s; r.y = g.x; r.z = g.y; r.w = 0u;
    rec[pos] = r;
}

// ---------------------------------------------------------------------------
// gather: one wave per dst node, lane = output feature, unroll x4 for MLP.
// ---------------------------------------------------------------------------
__global__ __launch_bounds__(256) void gather_kernel(
    const int* __restrict__ row_start, const uint4* __restrict__ rec,
    const unsigned short* __restrict__ hb,
    const float* __restrict__ feat, const float* __restrict__ bias,
    float* __restrict__ out, int n_nodes)
{
    const int lane = threadIdx.x & 63;
    const int v = (blockIdx.x * 256 + threadIdx.x) >> 6;
    if (v >= n_nodes) return;
    const int r0 = row_start[v];
    const int r1 = row_start[v + 1];
    float acc = 0.f;
    int j = r0;
    for (; j + 4 <= r1; j += 4) {
        const uint4 ra = rec[j+0];
        const uint4 rb = rec[j+1];
        const uint4 rc = rec[j+2];
        const uint4 rd = rec[j+3];
        const uint2 ha = *(const uint2*)(hb + (size_t)ra.x * 256 + lane * 4);
        const uint2 hbv= *(const uint2*)(hb + (size_t)rb.x * 256 + lane * 4);
        const uint2 hc = *(const uint2*)(hb + (size_t)rc.x * 256 + lane * 4);
        const uint2 hd = *(const uint2*)(hb + (size_t)rd.x * 256 + lane * 4);
        acc += bflo(ra.y)*bflo(ha.x) + bfhi(ra.y)*bfhi(ha.x)
             + bflo(ra.z)*bflo(ha.y) + bfhi(ra.z)*bfhi(ha.y);
        acc += bflo(rb.y)*bflo(hbv.x) + bfhi(rb.y)*bfhi(hbv.x)
             + bflo(rb.z)*bflo(hbv.y) + bfhi(rb.z)*bfhi(hbv.y);
        acc += bflo(rc.y)*bflo(hc.x) + bfhi(rc.y)*bfhi(hc.x)
             + bflo(rc.z)*bflo(hc.y) + bfhi(rc.z)*bfhi(hc.y);
        acc += bflo(rd.y)*bflo(hd.x) + bfhi(rd.y)*bfhi(hd.x)
             + bflo(rd.z)*bflo(hd.y) + bfhi(rd.z)*bfhi(hd.y);
    }
    for (; j < r1; ++j) {
        const uint4 ra = rec[j];
        const uint2 ha = *(const uint2*)(hb + (size_t)ra.x * 256 + lane * 4);
        acc += bflo(ra.y)*bflo(ha.x) + bfhi(ra.y)*bfhi(ha.x)
             + bflo(ra.z)*bflo(ha.y) + bfhi(ra.z)*bfhi(ha.y);
    }
    out[(size_t)v * OUT_F + lane] = acc + feat[(size_t)v * OUT_F + lane] + bias[lane];
}

extern "C" void kernel_launch(void* const* d_in, const int* in_sizes, int n_in,
                              void* d_out, int out_size, void* d_ws, size_t ws_size,
                              hipStream_t stream) {
    const float* feat      = (const float*)d_in[0];
    const float* pseudo    = (const float*)d_in[1];
    const int*   src       = (const int*)d_in[2];
    const int*   dst       = (const int*)d_in[3];
    const float* W_fc      = (const float*)d_in[4];
    const float* mu        = (const float*)d_in[5];
    const float* inv_sigma = (const float*)d_in[6];
    const float* bias      = (const float*)d_in[7];
    float* out = (float*)d_out;

    char* ws = (char*)d_ws;
    unsigned short* hb = (unsigned short*)ws;  ws += (size_t)N_NODES_C * 256 * 2;     // 51.2 MB
    uint2* g8          = (uint2*)ws;           ws += (size_t)N_EDGES_C * 8;           // 12.8 MB
    uint4* rec         = (uint4*)ws;           ws += (size_t)N_EDGES_C * 16;          // 25.6 MB
    int* cursor_pad    = (int*)ws;             ws += (size_t)N_NODES_C * CPAD * 4;    // 6.4 MB
    int* cnt           = (int*)ws;             ws += (size_t)N_NODES_C * 4;           // 0.4 MB
    int* row_start     = (int*)ws;             ws += (size_t)(N_NODES_C + 4) * 4;     // 0.4 MB
    int* bsum          = (int*)ws;             ws += 512 * 4;

    hipMemsetAsync(cnt, 0, (size_t)N_NODES_C * 4, stream);
    hist_gauss_kernel<<<EBLK, 256, 0, stream>>>(dst, pseudo, mu, inv_sigma, cnt, g8);
    proj_kernel<<<2048, 256, 0, stream>>>(feat, W_fc, hb, N_NODES_C);
    scan1_kernel<<<NBLK, SCAN_BLK, 0, stream>>>(cnt, bsum);
    scan23_kernel<<<NBLK, SCAN_BLK, 0, stream>>>(cnt, bsum, row_start, cursor_pad);
    scatter_kernel<<<EBLK, 256, 0, stream>>>(src, dst, g8, cursor_pad, rec);
    gather_kernel<<<(N_NODES_C * 64 + 255) / 256, 256, 0, stream>>>(
        row_start, rec, hb, feat, bias, out, N_NODES_C);
}

// Round 11
// 361.500 us; speedup vs baseline: 1.2797x; 1.0988x over previous
//
#include <hip/hip_runtime.h>

#define N_NODES_C 100000
#define N_EDGES_C 1600000
#define IN_F 64
#define OUT_F 64
#define NK 4
#define SCAN_BLK 256
#define NBLK ((N_NODES_C + SCAN_BLK - 1) / SCAN_BLK)   // 391
#define EBLK (N_EDGES_C / 256)                         // 6250 exact
#define CPAD 16                                        // cursor stride: 1 per 64B line
#define NSLICE 8
#define SLICE_N (N_NODES_C / NSLICE)                   // 12500 exact
#define SCAT_GRID 2048                                 // 256 blocks per slice

__device__ __forceinline__ unsigned int f2bf(float x) {
    unsigned int u = __float_as_uint(x);
    return (u + 0x7fffu + ((u >> 16) & 1u)) >> 16;
}
__device__ __forceinline__ float bflo(unsigned int u) { return __uint_as_float(u << 16); }
__device__ __forceinline__ float bfhi(unsigned int u) { return __uint_as_float(u & 0xffff0000u); }

// ---------------------------------------------------------------------------
// hist + gaussian weights, edge-parallel, fully coalesced
// ---------------------------------------------------------------------------
__global__ __launch_bounds__(256) void hist_gauss_kernel(
    const int* __restrict__ dst, const float* __restrict__ pseudo,
    const float* __restrict__ mu, const float* __restrict__ inv_sigma,
    int* __restrict__ cnt, uint2* __restrict__ g8)
{
    const int e = blockIdx.x * 256 + threadIdx.x;
    if (e >= N_EDGES_C) return;
    atomicAdd(&cnt[dst[e]], 1);
    const float p0 = pseudo[(size_t)e * 3 + 0];
    const float p1 = pseudo[(size_t)e * 3 + 1];
    const float p2 = pseudo[(size_t)e * 3 + 2];
    float g[NK];
    #pragma unroll
    for (int k = 0; k < NK; ++k) {
        const float d0 = p0 - mu[k*3+0], d1 = p1 - mu[k*3+1], d2 = p2 - mu[k*3+2];
        const float s0 = inv_sigma[k*3+0], s1 = inv_sigma[k*3+1], s2 = inv_sigma[k*3+2];
        const float ex = -0.5f * (d0*d0*s0*s0 + d1*d1*s1*s1 + d2*d2*s2*s2);
        g[k] = __expf(ex);
    }
    uint2 r;
    r.x = f2bf(g[0]) | (f2bf(g[1]) << 16);
    r.y = f2bf(g[2]) | (f2bf(g[3]) << 16);
    g8[e] = r;
}

// ---------------------------------------------------------------------------
// proj (R2 structure — no spill): thread t owns output col t=(o,k);
// scalar wreg[64]; feat row via LDS; coalesced 2B stores.
// ---------------------------------------------------------------------------
__global__ __launch_bounds__(256, 2) void proj_kernel(
    const float* __restrict__ feat, const float* __restrict__ W,
    unsigned short* __restrict__ hb, int n_nodes)
{
    __shared__ float frow[IN_F];
    const int t = threadIdx.x;
    const int o = t >> 2;
    const int k = t & 3;
    float wreg[IN_F];
    {
        const float4* W4 = reinterpret_cast<const float4*>(W + (size_t)(k * OUT_F + o) * IN_F);
        #pragma unroll
        for (int i = 0; i < IN_F / 4; ++i) {
            float4 v = W4[i];
            wreg[4*i+0] = v.x; wreg[4*i+1] = v.y; wreg[4*i+2] = v.z; wreg[4*i+3] = v.w;
        }
    }
    for (int n = blockIdx.x; n < n_nodes; n += gridDim.x) {
        if (t < IN_F / 4) {
            float4 v = reinterpret_cast<const float4*>(feat + (size_t)n * IN_F)[t];
            frow[4*t+0] = v.x; frow[4*t+1] = v.y; frow[4*t+2] = v.z; frow[4*t+3] = v.w;
        }
        __syncthreads();
        float acc = 0.f;
        #pragma unroll
        for (int i = 0; i < IN_F; ++i) acc = fmaf(frow[i], wreg[i], acc);
        hb[(size_t)n * 256 + t] = (unsigned short)f2bf(acc);
        __syncthreads();
    }
}

// ---------------------------------------------------------------------------
// scan1: per-block sums of cnt
// ---------------------------------------------------------------------------
__global__ __launch_bounds__(256) void scan1_kernel(
    const int* __restrict__ cnt, int* __restrict__ bsum)
{
    __shared__ int s[SCAN_BLK];
    int i = blockIdx.x * SCAN_BLK + threadIdx.x;
    int v = (i < N_NODES_C) ? cnt[i] : 0;
    s[threadIdx.x] = v; __syncthreads();
    for (int off = SCAN_BLK / 2; off > 0; off >>= 1) {
        if (threadIdx.x < off) s[threadIdx.x] += s[threadIdx.x + off];
        __syncthreads();
    }
    if (threadIdx.x == 0) bsum[blockIdx.x] = s[0];
}

// ---------------------------------------------------------------------------
// scan23: block-prefix over bsum + local exclusive scan -> row_start,
// padded cursor (one counter per 64B line)
// ---------------------------------------------------------------------------
__global__ __launch_bounds__(256) void scan23_kernel(
    const int* __restrict__ cnt, const int* __restrict__ bsum,
    int* __restrict__ row_start, int* __restrict__ cursor_pad)
{
    __shared__ int pre[SCAN_BLK];
    __shared__ int s[SCAN_BLK];
    const int t = threadIdx.x;
    int p = 0;
    for (int i = t; i < (int)blockIdx.x; i += SCAN_BLK) p += bsum[i];
    pre[t] = p; __syncthreads();
    for (int off = SCAN_BLK / 2; off > 0; off >>= 1) {
        if (t < off) pre[t] += pre[t + off];
        __syncthreads();
    }
    const int boff = pre[0];
    const int i = blockIdx.x * SCAN_BLK + t;
    int v = (i < N_NODES_C) ? cnt[i] : 0;
    s[t] = v; __syncthreads();
    for (int off = 1; off < SCAN_BLK; off <<= 1) {
        int x = (t >= off) ? s[t - off] : 0;
        __syncthreads();
        s[t] += x;
        __syncthreads();
    }
    if (i < N_NODES_C) {
        int ex = s[t] - v + boff;
        row_start[i] = ex;
        cursor_pad[(size_t)i * CPAD] = ex;
        if (i == N_NODES_C - 1) row_start[N_NODES_C] = ex + v;
    }
}

// ---------------------------------------------------------------------------
// XCD-sliced scatter: block b handles dst-slice (b&7); XCD dispatch heuristic
// (round-robin blockIdx%8) keeps each cursor/rec line written by ONE XCD ->
// no inter-XCD line migration. 8x coalesced re-read of dst/src/g8 is cheap.
// Slice regions: rec 3.2 MB, cursor 0.8 MB — both < 4 MB per-XCD L2.
// ---------------------------------------------------------------------------
__global__ __launch_bounds__(256) void scatter_kernel(
    const int* __restrict__ src, const int* __restrict__ dst,
    const uint2* __restrict__ g8, int* __restrict__ cursor_pad,
    uint4* __restrict__ rec)
{
    const int slice = (int)blockIdx.x & 7;
    const int w     = (int)blockIdx.x >> 3;          // 0..255 within slice
    const int lo = slice * SLICE_N, hi = lo + SLICE_N;
    for (int c = w; c < EBLK; c += SCAT_GRID / NSLICE) {
        const int e = c * 256 + (int)threadIdx.x;
        const int d = dst[e];
        if (d >= lo && d < hi) {
            const int s = src[e];
            const uint2 g = g8[e];
            const int pos = atomicAdd(&cursor_pad[(size_t)d * CPAD], 1);
            uint4 r; r.x = (unsigned int)s; r.y = g.x; r.z = g.y; r.w = 0u;
            rec[pos] = r;
        }
    }
}

// ---------------------------------------------------------------------------
// gather: one wave per dst node, lane = output feature, MLP x8 (static unroll)
// ---------------------------------------------------------------------------
__global__ __launch_bounds__(256, 2) void gather_kernel(
    const int* __restrict__ row_start, const uint4* __restrict__ rec,
    const unsigned short* __restrict__ hb,
    const float* __restrict__ feat, const float* __restrict__ bias,
    float* __restrict__ out, int n_nodes)
{
    const int lane = threadIdx.x & 63;
    const int v = (blockIdx.x * 256 + threadIdx.x) >> 6;
    if (v >= n_nodes) return;
    const int r0 = row_start[v];
    const int r1 = row_start[v + 1];
    float acc = 0.f;
    int j = r0;
    for (; j + 8 <= r1; j += 8) {
        uint4 rr[8];
        #pragma unroll
        for (int u = 0; u < 8; ++u) rr[u] = rec[j + u];
        uint2 hv[8];
        #pragma unroll
        for (int u = 0; u < 8; ++u)
            hv[u] = *(const uint2*)(hb + (size_t)rr[u].x * 256 + lane * 4);
        #pragma unroll
        for (int u = 0; u < 8; ++u) {
            acc += bflo(rr[u].y)*bflo(hv[u].x) + bfhi(rr[u].y)*bfhi(hv[u].x)
                 + bflo(rr[u].z)*bflo(hv[u].y) + bfhi(rr[u].z)*bfhi(hv[u].y);
        }
    }
    for (; j + 4 <= r1; j += 4) {
        uint4 rr[4];
        #pragma unroll
        for (int u = 0; u < 4; ++u) rr[u] = rec[j + u];
        uint2 hv[4];
        #pragma unroll
        for (int u = 0; u < 4; ++u)
            hv[u] = *(const uint2*)(hb + (size_t)rr[u].x * 256 + lane * 4);
        #pragma unroll
        for (int u = 0; u < 4; ++u) {
            acc += bflo(rr[u].y)*bflo(hv[u].x) + bfhi(rr[u].y)*bfhi(hv[u].x)
                 + bflo(rr[u].z)*bflo(hv[u].y) + bfhi(rr[u].z)*bfhi(hv[u].y);
        }
    }
    for (; j < r1; ++j) {
        const uint4 ra = rec[j];
        const uint2 ha = *(const uint2*)(hb + (size_t)ra.x * 256 + lane * 4);
        acc += bflo(ra.y)*bflo(ha.x) + bfhi(ra.y)*bfhi(ha.x)
             + bflo(ra.z)*bflo(ha.y) + bfhi(ra.z)*bfhi(ha.y);
    }
    out[(size_t)v * OUT_F + lane] = acc + feat[(size_t)v * OUT_F + lane] + bias[lane];
}

extern "C" void kernel_launch(void* const* d_in, const int* in_sizes, int n_in,
                              void* d_out, int out_size, void* d_ws, size_t ws_size,
                              hipStream_t stream) {
    const float* feat      = (const float*)d_in[0];
    const float* pseudo    = (const float*)d_in[1];
    const int*   src       = (const int*)d_in[2];
    const int*   dst       = (const int*)d_in[3];
    const float* W_fc      = (const float*)d_in[4];
    const float* mu        = (const float*)d_in[5];
    const float* inv_sigma = (const float*)d_in[6];
    const float* bias      = (const float*)d_in[7];
    float* out = (float*)d_out;

    char* ws = (char*)d_ws;
    unsigned short* hb = (unsigned short*)ws;  ws += (size_t)N_NODES_C * 256 * 2;     // 51.2 MB
    uint2* g8          = (uint2*)ws;           ws += (size_t)N_EDGES_C * 8;           // 12.8 MB
    uint4* rec         = (uint4*)ws;           ws += (size_t)N_EDGES_C * 16;          // 25.6 MB
    int* cursor_pad    = (int*)ws;             ws += (size_t)N_NODES_C * CPAD * 4;    // 6.4 MB
    int* cnt           = (int*)ws;             ws += (size_t)N_NODES_C * 4;           // 0.4 MB
    int* row_start     = (int*)ws;             ws += (size_t)(N_NODES_C + 4) * 4;     // 0.4 MB
    int* bsum          = (int*)ws;             ws += 512 * 4;

    hipMemsetAsync(cnt, 0, (size_t)N_NODES_C * 4, stream);
    hist_gauss_kernel<<<EBLK, 256, 0, stream>>>(dst, pseudo, mu, inv_sigma, cnt, g8);
    proj_kernel<<<2048, 256, 0, stream>>>(feat, W_fc, hb, N_NODES_C);
    scan1_kernel<<<NBLK, SCAN_BLK, 0, stream>>>(cnt, bsum);
    scan23_kernel<<<NBLK, SCAN_BLK, 0, stream>>>(cnt, bsum, row_start, cursor_pad);
    scatter_kernel<<<SCAT_GRID, 256, 0, stream>>>(src, dst, g8, cursor_pad, rec);
    gather_kernel<<<(N_NODES_C * 64 + 255) / 256, 256, 0, stream>>>(
        row_start, rec, hb, feat, bias, out, N_NODES_C);
}

// Round 12
// 355.593 us; speedup vs baseline: 1.3010x; 1.0166x over previous
//
#include <hip/hip_runtime.h>

#define N_NODES_C 100000
#define N_EDGES_C 1600000
#define IN_F 64
#define OUT_F 64
#define NK 4
#define SCAN_BLK 256
#define NBLK ((N_NODES_C + SCAN_BLK - 1) / SCAN_BLK)   // 391
#define EBLK (N_EDGES_C / 256)                         // 6250 exact
#define CPAD 16                                        // cursor stride: 1 per 64B line
#define NSLICE 8
#define SLICE_N (N_NODES_C / NSLICE)                   // 12500 exact
#define SCAT_GRID 2048                                 // 256 blocks per slice

__device__ __forceinline__ unsigned int f2bf(float x) {
    unsigned int u = __float_as_uint(x);
    return (u + 0x7fffu + ((u >> 16) & 1u)) >> 16;
}
__device__ __forceinline__ float bflo(unsigned int u) { return __uint_as_float(u << 16); }
__device__ __forceinline__ float bfhi(unsigned int u) { return __uint_as_float(u & 0xffff0000u); }

// ---------------------------------------------------------------------------
// hist + gaussian weights, edge-parallel, fully coalesced
// ---------------------------------------------------------------------------
__global__ __launch_bounds__(256) void hist_gauss_kernel(
    const int* __restrict__ dst, const float* __restrict__ pseudo,
    const float* __restrict__ mu, const float* __restrict__ inv_sigma,
    int* __restrict__ cnt, uint2* __restrict__ g8)
{
    const int e = blockIdx.x * 256 + threadIdx.x;
    if (e >= N_EDGES_C) return;
    atomicAdd(&cnt[dst[e]], 1);
    const float p0 = pseudo[(size_t)e * 3 + 0];
    const float p1 = pseudo[(size_t)e * 3 + 1];
    const float p2 = pseudo[(size_t)e * 3 + 2];
    float g[NK];
    #pragma unroll
    for (int k = 0; k < NK; ++k) {
        const float d0 = p0 - mu[k*3+0], d1 = p1 - mu[k*3+1], d2 = p2 - mu[k*3+2];
        const float s0 = inv_sigma[k*3+0], s1 = inv_sigma[k*3+1], s2 = inv_sigma[k*3+2];
        const float ex = -0.5f * (d0*d0*s0*s0 + d1*d1*s1*s1 + d2*d2*s2*s2);
        g[k] = __expf(ex);
    }
    uint2 r;
    r.x = f2bf(g[0]) | (f2bf(g[1]) << 16);
    r.y = f2bf(g[2]) | (f2bf(g[3]) << 16);
    g8[e] = r;
}

// ---------------------------------------------------------------------------
// proj: 2 nodes/iter, 4 independent FMA chains, scalar wreg[64] (R2-proven
// structure -> sane regalloc). Coalesced 2B stores.
// ---------------------------------------------------------------------------
__global__ __launch_bounds__(256, 2) void proj_kernel(
    const float* __restrict__ feat, const float* __restrict__ W,
    unsigned short* __restrict__ hb, int n_nodes)
{
    __shared__ float frow[2][IN_F];
    const int t = threadIdx.x;
    const int o = t >> 2;
    const int k = t & 3;
    float wreg[IN_F];
    {
        const float4* W4 = reinterpret_cast<const float4*>(W + (size_t)(k * OUT_F + o) * IN_F);
        #pragma unroll
        for (int i = 0; i < IN_F / 4; ++i) {
            float4 v = W4[i];
            wreg[4*i+0] = v.x; wreg[4*i+1] = v.y; wreg[4*i+2] = v.z; wreg[4*i+3] = v.w;
        }
    }
    const int nn2 = n_nodes >> 1;   // 50000 (n_nodes even)
    for (int q = blockIdx.x; q < nn2; q += gridDim.x) {
        const int n0 = q << 1;
        if (t < 32) {   // 32 float4 = 128 floats = 2 rows
            float4 v = reinterpret_cast<const float4*>(feat + (size_t)n0 * IN_F)[t];
            const int r = t >> 4, c = (t & 15) * 4;
            frow[r][c+0] = v.x; frow[r][c+1] = v.y; frow[r][c+2] = v.z; frow[r][c+3] = v.w;
        }
        __syncthreads();
        float a0 = 0.f, b0 = 0.f, a1 = 0.f, b1 = 0.f;
        #pragma unroll
        for (int i = 0; i < IN_F; i += 2) {
            a0 = fmaf(frow[0][i],   wreg[i],   a0);
            b0 = fmaf(frow[0][i+1], wreg[i+1], b0);
            a1 = fmaf(frow[1][i],   wreg[i],   a1);
            b1 = fmaf(frow[1][i+1], wreg[i+1], b1);
        }
        hb[(size_t)n0 * 256 + t]       = (unsigned short)f2bf(a0 + b0);
        hb[(size_t)(n0 + 1) * 256 + t] = (unsigned short)f2bf(a1 + b1);
        __syncthreads();
    }
}

// ---------------------------------------------------------------------------
// scan1: per-block sums of cnt
// ---------------------------------------------------------------------------
__global__ __launch_bounds__(256) void scan1_kernel(
    const int* __restrict__ cnt, int* __restrict__ bsum)
{
    __shared__ int s[SCAN_BLK];
    int i = blockIdx.x * SCAN_BLK + threadIdx.x;
    int v = (i < N_NODES_C) ? cnt[i] : 0;
    s[threadIdx.x] = v; __syncthreads();
    for (int off = SCAN_BLK / 2; off > 0; off >>= 1) {
        if (threadIdx.x < off) s[threadIdx.x] += s[threadIdx.x + off];
        __syncthreads();
    }
    if (threadIdx.x == 0) bsum[blockIdx.x] = s[0];
}

// ---------------------------------------------------------------------------
// scan23: block-prefix over bsum + local exclusive scan -> row_start,
// padded cursor (one counter per 64B line)
// ---------------------------------------------------------------------------
__global__ __launch_bounds__(256) void scan23_kernel(
    const int* __restrict__ cnt, const int* __restrict__ bsum,
    int* __restrict__ row_start, int* __restrict__ cursor_pad)
{
    __shared__ int pre[SCAN_BLK];
    __shared__ int s[SCAN_BLK];
    const int t = threadIdx.x;
    int p = 0;
    for (int i = t; i < (int)blockIdx.x; i += SCAN_BLK) p += bsum[i];
    pre[t] = p; __syncthreads();
    for (int off = SCAN_BLK / 2; off > 0; off >>= 1) {
        if (t < off) pre[t] += pre[t + off];
        __syncthreads();
    }
    const int boff = pre[0];
    const int i = blockIdx.x * SCAN_BLK + t;
    int v = (i < N_NODES_C) ? cnt[i] : 0;
    s[t] = v; __syncthreads();
    for (int off = 1; off < SCAN_BLK; off <<= 1) {
        int x = (t >= off) ? s[t - off] : 0;
        __syncthreads();
        s[t] += x;
        __syncthreads();
    }
    if (i < N_NODES_C) {
        int ex = s[t] - v + boff;
        row_start[i] = ex;
        cursor_pad[(size_t)i * CPAD] = ex;
        if (i == N_NODES_C - 1) row_start[N_NODES_C] = ex + v;
    }
}

// ---------------------------------------------------------------------------
// XCD-sliced scatter (R11, unchanged): block b handles dst-slice (b&7);
// round-robin dispatch keeps each cursor/rec line written by ONE XCD.
// ---------------------------------------------------------------------------
__global__ __launch_bounds__(256) void scatter_kernel(
    const int* __restrict__ src, const int* __restrict__ dst,
    const uint2* __restrict__ g8, int* __restrict__ cursor_pad,
    uint4* __restrict__ rec)
{
    const int slice = (int)blockIdx.x & 7;
    const int w     = (int)blockIdx.x >> 3;          // 0..255 within slice
    const int lo = slice * SLICE_N, hi = lo + SLICE_N;
    for (int c = w; c < EBLK; c += SCAT_GRID / NSLICE) {
        const int e = c * 256 + (int)threadIdx.x;
        const int d = dst[e];
        if (d >= lo && d < hi) {
            const int s = src[e];
            const uint2 g = g8[e];
            const int pos = atomicAdd(&cursor_pad[(size_t)d * CPAD], 1);
            uint4 r; r.x = (unsigned int)s; r.y = g.x; r.z = g.y; r.w = 0u;
            rec[pos] = r;
        }
    }
}

// ---------------------------------------------------------------------------
// gather: TWO waves per dst node (contiguous half-split), LDS combine.
// Halves each wave's dependent-load chain, doubles independent chains.
// ---------------------------------------------------------------------------
__global__ __launch_bounds__(256, 2) void gather_kernel(
    const int* __restrict__ row_start, const uint4* __restrict__ rec,
    const unsigned short* __restrict__ hb,
    const float* __restrict__ feat, const float* __restrict__ bias,
    float* __restrict__ out, int n_nodes)
{
    __shared__ float part[2][64];
    const int lane = threadIdx.x & 63;
    const int w    = threadIdx.x >> 6;            // 0..3
    const int pair = w >> 1;                      // 0..1 (node within block)
    const int half = w & 1;
    const int v = (int)blockIdx.x * 2 + pair;
    float acc = 0.f;
    int r0 = 0, r1 = 0;
    if (v < n_nodes) { r0 = row_start[v]; r1 = row_start[v + 1]; }
    const int mid = (r0 + r1 + 1) >> 1;
    int j        = half ? mid : r0;
    const int je = half ? r1  : mid;
    for (; j + 4 <= je; j += 4) {
        uint4 rr[4];
        #pragma unroll
        for (int u = 0; u < 4; ++u) rr[u] = rec[j + u];
        uint2 hv[4];
        #pragma unroll
        for (int u = 0; u < 4; ++u)
            hv[u] = *(const uint2*)(hb + (size_t)rr[u].x * 256 + lane * 4);
        #pragma unroll
        for (int u = 0; u < 4; ++u) {
            acc += bflo(rr[u].y)*bflo(hv[u].x) + bfhi(rr[u].y)*bfhi(hv[u].x)
                 + bflo(rr[u].z)*bflo(hv[u].y) + bfhi(rr[u].z)*bfhi(hv[u].y);
        }
    }
    for (; j < je; ++j) {
        const uint4 ra = rec[j];
        const uint2 ha = *(const uint2*)(hb + (size_t)ra.x * 256 + lane * 4);
        acc += bflo(ra.y)*bflo(ha.x) + bfhi(ra.y)*bfhi(ha.x)
             + bflo(ra.z)*bflo(ha.y) + bfhi(ra.z)*bfhi(ha.y);
    }
    if (half) part[pair][lane] = acc;
    __syncthreads();
    if (!half && v < n_nodes) {
        out[(size_t)v * OUT_F + lane] =
            acc + part[pair][lane] + feat[(size_t)v * OUT_F + lane] + bias[lane];
    }
}

extern "C" void kernel_launch(void* const* d_in, const int* in_sizes, int n_in,
                              void* d_out, int out_size, void* d_ws, size_t ws_size,
                              hipStream_t stream) {
    const float* feat      = (const float*)d_in[0];
    const float* pseudo    = (const float*)d_in[1];
    const int*   src       = (const int*)d_in[2];
    const int*   dst       = (const int*)d_in[3];
    const float* W_fc      = (const float*)d_in[4];
    const float* mu        = (const float*)d_in[5];
    const float* inv_sigma = (const float*)d_in[6];
    const float* bias      = (const float*)d_in[7];
    float* out = (float*)d_out;

    char* ws = (char*)d_ws;
    unsigned short* hb = (unsigned short*)ws;  ws += (size_t)N_NODES_C * 256 * 2;     // 51.2 MB
    uint2* g8          = (uint2*)ws;           ws += (size_t)N_EDGES_C * 8;           // 12.8 MB
    uint4* rec         = (uint4*)ws;           ws += (size_t)N_EDGES_C * 16;          // 25.6 MB
    int* cursor_pad    = (int*)ws;             ws += (size_t)N_NODES_C * CPAD * 4;    // 6.4 MB
    int* cnt           = (int*)ws;             ws += (size_t)N_NODES_C * 4;           // 0.4 MB
    int* row_start     = (int*)ws;             ws += (size_t)(N_NODES_C + 4) * 4;     // 0.4 MB
    int* bsum          = (int*)ws;             ws += 512 * 4;

    hipMemsetAsync(cnt, 0, (size_t)N_NODES_C * 4, stream);
    hist_gauss_kernel<<<EBLK, 256, 0, stream>>>(dst, pseudo, mu, inv_sigma, cnt, g8);
    proj_kernel<<<2048, 256, 0, stream>>>(feat, W_fc, hb, N_NODES_C);
    scan1_kernel<<<NBLK, SCAN_BLK, 0, stream>>>(cnt, bsum);
    scan23_kernel<<<NBLK, SCAN_BLK, 0, stream>>>(cnt, bsum, row_start, cursor_pad);
    scatter_kernel<<<SCAT_GRID, 256, 0, stream>>>(src, dst, g8, cursor_pad, rec);
    gather_kernel<<<(N_NODES_C + 1) / 2, 256, 0, stream>>>(
        row_start, rec, hb, feat, bias, out, N_NODES_C);
}